// Round 7
// baseline (345.873 us; speedup 1.0000x reference)
//
#include <hip/hip_runtime.h>

// Inputs and outputs are float32 (established R1/R3).
#define NCLS 91
#define W1_LD 2052   // repn_w1 row length (2C+4)

// ---------- K1: p[i][r] = feats[i] . Wcomb[r] ----------
// Wcomb rows 0..255 = wf1, 256..511 = wf2 (both K=1024 slices of repn_w1).
// No LDS: A float4 broadcast across the 16 n-lanes, B rows streamed (L1-cached).
// grid (8 r-slices, 32 i-tiles), 256 thr; thread = 1 row x 4 cols.
__global__ __launch_bounds__(256) void k_p12(const float* __restrict__ feats,
                                             const float* __restrict__ w1f,
                                             float* __restrict__ p) {
    int t = threadIdx.x;
    int i = blockIdx.y * 16 + (t >> 4);
    int rc = blockIdx.x * 64 + (t & 15) * 4;
    const float* arow = feats + i * 1024;
    const float* w0 = w1f + (rc < 256 ? (rc + 0) * W1_LD : (rc - 256 + 0) * W1_LD + 1024);
    const float* w1 = w1f + (rc < 256 ? (rc + 1) * W1_LD : (rc - 256 + 1) * W1_LD + 1024);
    const float* w2 = w1f + (rc < 256 ? (rc + 2) * W1_LD : (rc - 256 + 2) * W1_LD + 1024);
    const float* w3 = w1f + (rc < 256 ? (rc + 3) * W1_LD : (rc - 256 + 3) * W1_LD + 1024);
    float4 acc = make_float4(0.f, 0.f, 0.f, 0.f);
#pragma unroll 2
    for (int k = 0; k < 1024; k += 4) {
        float4 a4 = *(const float4*)(arow + k);
        float4 b0 = *(const float4*)(w0 + k);
        float4 b1 = *(const float4*)(w1 + k);
        float4 b2 = *(const float4*)(w2 + k);
        float4 b3 = *(const float4*)(w3 + k);
        acc.x = fmaf(a4.x, b0.x, acc.x); acc.x = fmaf(a4.y, b0.y, acc.x);
        acc.x = fmaf(a4.z, b0.z, acc.x); acc.x = fmaf(a4.w, b0.w, acc.x);
        acc.y = fmaf(a4.x, b1.x, acc.y); acc.y = fmaf(a4.y, b1.y, acc.y);
        acc.y = fmaf(a4.z, b1.z, acc.y); acc.y = fmaf(a4.w, b1.w, acc.y);
        acc.z = fmaf(a4.x, b2.x, acc.z); acc.z = fmaf(a4.y, b2.y, acc.z);
        acc.z = fmaf(a4.z, b2.z, acc.z); acc.z = fmaf(a4.w, b2.w, acc.z);
        acc.w = fmaf(a4.x, b3.x, acc.w); acc.w = fmaf(a4.y, b3.y, acc.w);
        acc.w = fmaf(a4.z, b3.z, acc.w); acc.w = fmaf(a4.w, b3.w, acc.w);
    }
    *(float4*)(p + i * 512 + rc) = acc;
}

// ---------- K2: rel[i][j] — 16i x 64j tile over 256-dim h ----------
__global__ __launch_bounds__(256) void k_rel(const float* __restrict__ p,
                                             const float* __restrict__ w1f,
                                             const float* __restrict__ b1f,
                                             const float* __restrict__ w2f,
                                             const float* __restrict__ b2f,
                                             const float* __restrict__ boxesf,
                                             float* __restrict__ rel_out) {
    int j0 = blockIdx.x * 64, i0 = blockIdx.y * 16;
    int tid = threadIdx.x, tx = tid & 63, ty = tid >> 6;
    __shared__ float As1[32 * 17];
    __shared__ float Bs[32 * 64];
    __shared__ float Awg[32 * 4];
    __shared__ float Aw2[32];
    float4 bj = *(const float4*)(boxesf + (j0 + tx) * 4);
    float g[4][4];
#pragma unroll
    for (int s = 0; s < 4; ++s) {
        float4 bi = *(const float4*)(boxesf + (i0 + ty * 4 + s) * 4);
        g[s][0] = fabsf(bi.x - bj.x); g[s][1] = fabsf(bi.y - bj.y);
        g[s][2] = fabsf(bi.z - bj.z); g[s][3] = fabsf(bi.w - bj.w);
    }
    float acc[4] = {0.f, 0.f, 0.f, 0.f};
    int ali = tid & 15, alh = (tid >> 4) * 4;
    int blj = tid & 63, blh = (tid >> 6) * 8;
    for (int ch = 0; ch < 8; ++ch) {
        int hb = ch * 32;
        if (tid < 128) {
            float4 v = *(const float4*)(p + (i0 + ali) * 512 + hb + alh);
            float4 b = *(const float4*)(b1f + hb + alh);
            As1[(alh + 0) * 17 + ali] = v.x + b.x;
            As1[(alh + 1) * 17 + ali] = v.y + b.y;
            As1[(alh + 2) * 17 + ali] = v.z + b.z;
            As1[(alh + 3) * 17 + ali] = v.w + b.w;
        }
#pragma unroll
        for (int s = 0; s < 2; ++s) {
            int h = blh + 4 * s;
            float4 u = *(const float4*)(p + (j0 + blj) * 512 + 256 + hb + h);
            Bs[(h + 0) * 64 + blj] = u.x;
            Bs[(h + 1) * 64 + blj] = u.y;
            Bs[(h + 2) * 64 + blj] = u.z;
            Bs[(h + 3) * 64 + blj] = u.w;
        }
        if (tid < 32) {
            int hg = hb + tid;
            *(float4*)(Awg + tid * 4) = *(const float4*)(w1f + hg * W1_LD + 2048);
            Aw2[tid] = w2f[hg];
        }
        __syncthreads();
#pragma unroll
        for (int hh = 0; hh < 32; ++hh) {
            float4 wg = *(const float4*)(Awg + hh * 4);
            float w2v = Aw2[hh];
            float p2v = Bs[hh * 64 + tx];
            float s0 = As1[hh * 17 + ty * 4 + 0];
            float s1 = As1[hh * 17 + ty * 4 + 1];
            float s2 = As1[hh * 17 + ty * 4 + 2];
            float s3 = As1[hh * 17 + ty * 4 + 3];
            float t0 = s0 + p2v;
            t0 = fmaf(g[0][0], wg.x, t0); t0 = fmaf(g[0][1], wg.y, t0);
            t0 = fmaf(g[0][2], wg.z, t0); t0 = fmaf(g[0][3], wg.w, t0);
            acc[0] = fmaf(w2v, fmaxf(t0, 0.f), acc[0]);
            float t1 = s1 + p2v;
            t1 = fmaf(g[1][0], wg.x, t1); t1 = fmaf(g[1][1], wg.y, t1);
            t1 = fmaf(g[1][2], wg.z, t1); t1 = fmaf(g[1][3], wg.w, t1);
            acc[1] = fmaf(w2v, fmaxf(t1, 0.f), acc[1]);
            float t2 = s2 + p2v;
            t2 = fmaf(g[2][0], wg.x, t2); t2 = fmaf(g[2][1], wg.y, t2);
            t2 = fmaf(g[2][2], wg.z, t2); t2 = fmaf(g[2][3], wg.w, t2);
            acc[2] = fmaf(w2v, fmaxf(t2, 0.f), acc[2]);
            float t3 = s3 + p2v;
            t3 = fmaf(g[3][0], wg.x, t3); t3 = fmaf(g[3][1], wg.y, t3);
            t3 = fmaf(g[3][2], wg.z, t3); t3 = fmaf(g[3][3], wg.w, t3);
            acc[3] = fmaf(w2v, fmaxf(t3, 0.f), acc[3]);
        }
        __syncthreads();
    }
    float b2v = b2f[0];
#pragma unroll
    for (int s = 0; s < 4; ++s)
        rel_out[(i0 + ty * 4 + s) * 512 + j0 + tx] = acc[s] + b2v;
}

// ---------- K3: per-row top-(k+1), drop first; count in-degrees ----------
__global__ void k_topk(const float* __restrict__ relf, const int* __restrict__ kp,
                       int* __restrict__ nbrs, int* __restrict__ count) {
    int i = blockIdx.x, lane = threadIdx.x;
    int k = *kp;
    float v[8]; int ids[8];
    for (int q = 0; q < 8; ++q) {
        int j = lane + 64 * q;
        v[q] = relf[i * 512 + j];
        ids[q] = j;
    }
    for (int pick = 0; pick < k + 1; ++pick) {
        float bv = -INFINITY; int bidx = 1 << 30;
        for (int q = 0; q < 8; ++q)
            if (v[q] > bv || (v[q] == bv && ids[q] < bidx)) { bv = v[q]; bidx = ids[q]; }
        for (int off = 32; off > 0; off >>= 1) {
            float ov = __shfl_down(bv, off);
            int oi = __shfl_down(bidx, off);
            if (ov > bv || (ov == bv && oi < bidx)) { bv = ov; bidx = oi; }
        }
        bv = __shfl(bv, 0); bidx = __shfl(bidx, 0);
        if (pick >= 1 && lane == 0) {
            nbrs[i * 8 + (pick - 1)] = bidx;
            atomicAdd(&count[bidx], 1);
        }
        for (int q = 0; q < 8; ++q) if (ids[q] == bidx) v[q] = -INFINITY;
    }
    if (lane == 0) atomicAdd(&count[i], 1);
}

// ---------- K4: exclusive scan ----------
__global__ void k_scan(const int* __restrict__ count, int* __restrict__ offs) {
    __shared__ int s[512];
    int t = threadIdx.x;
    s[t] = count[t];
    __syncthreads();
    for (int off = 1; off < 512; off <<= 1) {
        int v = (t >= off) ? s[t - off] : 0;
        __syncthreads();
        s[t] += v;
        __syncthreads();
    }
    offs[t + 1] = s[t];
    if (t == 0) offs[0] = 0;
}

// ---------- K5: fill in-edge lists ----------
__global__ void k_fill(const int* __restrict__ nbrs, const int* __restrict__ kp,
                       const int* __restrict__ offs, int* __restrict__ cursor,
                       int* __restrict__ inlist) {
    int i = blockIdx.x * blockDim.x + threadIdx.x;
    if (i >= 512) return;
    int k = *kp;
    for (int q = 0; q < k; ++q) {
        int d = nbrs[i * 8 + q] & 511;
        int pos = atomicAdd(&cursor[d], 1);
        inlist[offs[d] + pos] = i;
    }
    int pos = atomicAdd(&cursor[i], 1);
    inlist[offs[i] + pos] = i;
}

// ---------- K6: GAT1 GEMM hX = [feats|geom] @ W, streaming (no LDS) ----------
// grid (16 n-slices, 32 i-tiles), 256 thr; thread = 1 row x 4 cols; geom epilogue.
__global__ __launch_bounds__(256) void k_gat1(const float* __restrict__ feats,
                                              const float* __restrict__ boxesf,
                                              const float* __restrict__ Wg,
                                              float* __restrict__ hX) {
    int t = threadIdx.x;
    int i = blockIdx.y * 16 + (t >> 4);
    int nc = blockIdx.x * 64 + (t & 15) * 4;
    const float* arow = feats + i * 1024;
    const float* bcol = Wg + nc;
    float4 acc = make_float4(0.f, 0.f, 0.f, 0.f);
#pragma unroll 2
    for (int k = 0; k < 1024; k += 4) {
        float4 a4 = *(const float4*)(arow + k);
        float4 b0 = *(const float4*)(bcol + (k + 0) * 1024);
        float4 b1 = *(const float4*)(bcol + (k + 1) * 1024);
        float4 b2 = *(const float4*)(bcol + (k + 2) * 1024);
        float4 b3 = *(const float4*)(bcol + (k + 3) * 1024);
        acc.x = fmaf(a4.x, b0.x, acc.x); acc.y = fmaf(a4.x, b0.y, acc.y);
        acc.z = fmaf(a4.x, b0.z, acc.z); acc.w = fmaf(a4.x, b0.w, acc.w);
        acc.x = fmaf(a4.y, b1.x, acc.x); acc.y = fmaf(a4.y, b1.y, acc.y);
        acc.z = fmaf(a4.y, b1.z, acc.z); acc.w = fmaf(a4.y, b1.w, acc.w);
        acc.x = fmaf(a4.z, b2.x, acc.x); acc.y = fmaf(a4.z, b2.y, acc.y);
        acc.z = fmaf(a4.z, b2.z, acc.z); acc.w = fmaf(a4.z, b2.w, acc.w);
        acc.x = fmaf(a4.w, b3.x, acc.x); acc.y = fmaf(a4.w, b3.y, acc.y);
        acc.z = fmaf(a4.w, b3.z, acc.z); acc.w = fmaf(a4.w, b3.w, acc.w);
    }
    // geom rows 1024..1027
    float4 bx = *(const float4*)(boxesf + i * 4);
    float g0 = bx.x / 800.f, g1 = bx.y / 800.f;
    float g2 = bx.z / 800.f - g0, g3 = bx.w / 800.f - g1;
    float4 w0 = *(const float4*)(bcol + 1024 * 1024);
    float4 w1 = *(const float4*)(bcol + 1025 * 1024);
    float4 w2 = *(const float4*)(bcol + 1026 * 1024);
    float4 w3 = *(const float4*)(bcol + 1027 * 1024);
    acc.x += g0 * w0.x + g1 * w1.x + g2 * w2.x + g3 * w3.x;
    acc.y += g0 * w0.y + g1 * w1.y + g2 * w2.y + g3 * w3.y;
    acc.z += g0 * w0.z + g1 * w1.z + g2 * w2.z + g3 * w3.z;
    acc.w += g0 * w0.w + g1 * w1.w + g2 * w2.w + g3 * w3.w;
    *(float4*)(hX + i * 1024 + nc) = acc;
}

// ---------- K6b: a_s1/a_d1 reduction from hX (512 blocks x 256 thr) ----------
__global__ __launch_bounds__(256) void k_gred(const float* __restrict__ hX,
                                              const float* __restrict__ asrcf,
                                              const float* __restrict__ adstf,
                                              float* __restrict__ a_s1,
                                              float* __restrict__ a_d1) {
    int i = blockIdx.x, t = threadIdx.x;
    int c = t * 4;
    float4 v = *(const float4*)(hX + i * 1024 + c);
    float4 as4 = *(const float4*)(asrcf + c);
    float4 ad4 = *(const float4*)(adstf + c);
    float ps = v.x * as4.x + v.y * as4.y + v.z * as4.z + v.w * as4.w;
    float pd = v.x * ad4.x + v.y * ad4.y + v.z * ad4.z + v.w * ad4.w;
    int lane = t & 63, q = t >> 6;   // wave q == head q
    for (int off = 32; off > 0; off >>= 1) {
        ps += __shfl_down(ps, off);
        pd += __shfl_down(pd, off);
    }
    if (lane == 0) {
        a_s1[i * 4 + q] = ps;
        a_d1[i * 4 + q] = pd;
    }
}

// ---------- K8: GAT1 per-dst softmax + aggregate + bias + relu ----------
__global__ void k_aggr1(const float* __restrict__ hX,
                        const float* __restrict__ a_s, const float* __restrict__ a_d,
                        const int* __restrict__ offs, const int* __restrict__ inlist,
                        const float* __restrict__ bias,
                        float* __restrict__ h1) {
    int n = blockIdx.x, t = threadIdx.x;
    int beg = offs[n], deg = offs[n + 1] - beg;
    if (deg > 513) deg = 513;
    __shared__ int srcs[520];
    __shared__ float alpha[520][4];
    __shared__ float sm[4];
    for (int e = t; e < deg; e += 256) srcs[e] = inlist[beg + e] & 511;
    __syncthreads();
    for (int idx = t; idx < deg * 4; idx += 256) {
        int e = idx >> 2, q = idx & 3;
        float sc = a_s[srcs[e] * 4 + q] + a_d[n * 4 + q];
        alpha[e][q] = (sc >= 0.f) ? sc : 0.2f * sc;
    }
    __syncthreads();
    if (t < 4) {
        float m = -INFINITY;
        for (int e = 0; e < deg; ++e) m = fmaxf(m, alpha[e][t]);
        if (!isfinite(m)) m = 0.f;
        float s = 0.f;
        for (int e = 0; e < deg; ++e) { float ex = expf(alpha[e][t] - m); alpha[e][t] = ex; s += ex; }
        sm[t] = s + 1e-16f;
    }
    __syncthreads();
    for (int idx = t; idx < deg * 4; idx += 256) {
        int e = idx >> 2, q = idx & 3;
        alpha[e][q] /= sm[q];
    }
    __syncthreads();
    for (int q = 0; q < 4; ++q) {
        float acc = 0.f;
        for (int e = 0; e < deg; ++e) acc += alpha[e][q] * hX[srcs[e] * 1024 + q * 256 + t];
        h1[n * 1024 + q * 256 + t] = fmaxf(acc + bias[q * 256 + t], 0.f);
    }
}

// ---------- K9: GAT2 GEMM + a_s2/a_d2 ----------
__global__ __launch_bounds__(256) void k_gat2(const float* __restrict__ h1,
                                              const float* __restrict__ Wf,
                                              const float* __restrict__ asrcf,
                                              const float* __restrict__ adstf,
                                              float* __restrict__ h2,
                                              float* __restrict__ a_s2,
                                              float* __restrict__ a_d2) {
    int n = blockIdx.x, t = threadIdx.x;
    __shared__ float xs[1024];
    __shared__ float hbuf[NCLS];
    __shared__ float sred[256], dred[256];
    for (int c = t; c < 1024; c += 256) xs[c] = h1[n * 1024 + c];
    __syncthreads();
    int cls = t & 127, kh = t >> 7;
    float acc = 0.f;
    if (cls < NCLS) {
        const float* wp = Wf + (kh * 512) * NCLS + cls;
        const float* xp = xs + kh * 512;
        float a0 = 0.f, a1 = 0.f, a2 = 0.f, a3 = 0.f;
        for (int c = 0; c < 512; c += 4) {
            a0 = fmaf(xp[c + 0], wp[(c + 0) * NCLS], a0);
            a1 = fmaf(xp[c + 1], wp[(c + 1) * NCLS], a1);
            a2 = fmaf(xp[c + 2], wp[(c + 2) * NCLS], a2);
            a3 = fmaf(xp[c + 3], wp[(c + 3) * NCLS], a3);
        }
        acc = (a0 + a1) + (a2 + a3);
    }
    if (kh == 0 && cls < NCLS) hbuf[cls] = acc;
    __syncthreads();
    float tot = 0.f;
    int act = (kh == 1 && cls < NCLS);
    if (act) { tot = acc + hbuf[cls]; h2[n * NCLS + cls] = tot; }
    sred[t] = act ? tot * asrcf[cls] : 0.f;
    dred[t] = act ? tot * adstf[cls] : 0.f;
    __syncthreads();
    for (int s = 128; s > 0; s >>= 1) {
        if (t < s) { sred[t] += sred[t + s]; dred[t] += dred[t + s]; }
        __syncthreads();
    }
    if (t == 0) { a_s2[n] = sred[0]; a_d2[n] = dred[0]; }
}

// ---------- K10: GAT2 aggregate -> logits + softmax probs ----------
__global__ void k_aggr2(const float* __restrict__ h2,
                        const float* __restrict__ a_s2, const float* __restrict__ a_d2,
                        const int* __restrict__ offs, const int* __restrict__ inlist,
                        const float* __restrict__ bias,
                        float* __restrict__ logits_out,
                        float* __restrict__ probs_out) {
    int n = blockIdx.x, t = threadIdx.x;
    int beg = offs[n], deg = offs[n + 1] - beg;
    if (deg > 513) deg = 513;
    __shared__ int srcs[520];
    __shared__ float alpha[520];
    __shared__ float red[128];
    __shared__ float smden;
    for (int e = t; e < deg; e += 128) {
        int s = inlist[beg + e] & 511;
        srcs[e] = s;
        float sc = a_s2[s] + a_d2[n];
        alpha[e] = (sc >= 0.f) ? sc : 0.2f * sc;
    }
    __syncthreads();
    if (t == 0) {
        float m = -INFINITY;
        for (int e = 0; e < deg; ++e) m = fmaxf(m, alpha[e]);
        if (!isfinite(m)) m = 0.f;
        float s = 0.f;
        for (int e = 0; e < deg; ++e) { float ex = expf(alpha[e] - m); alpha[e] = ex; s += ex; }
        smden = s + 1e-16f;
    }
    __syncthreads();
    float logit = 0.f;
    if (t < NCLS) {
        float acc = 0.f;
        for (int e = 0; e < deg; ++e) acc += alpha[e] * h2[srcs[e] * NCLS + t];
        logit = acc / smden + bias[t];
        logits_out[n * NCLS + t] = logit;
    }
    red[t] = (t < NCLS) ? logit : -INFINITY; __syncthreads();
    for (int s = 64; s > 0; s >>= 1) { if (t < s) red[t] = fmaxf(red[t], red[t + s]); __syncthreads(); }
    float mx = red[0];
    __syncthreads();
    float ex = (t < NCLS) ? expf(logit - mx) : 0.f;
    red[t] = ex; __syncthreads();
    for (int s = 64; s > 0; s >>= 1) { if (t < s) red[t] += red[t + s]; __syncthreads(); }
    float inv = 1.f / red[0];
    if (t < NCLS) probs_out[n * NCLS + t] = ex * inv;
}

// ---------- launch ----------
extern "C" void kernel_launch(void* const* d_in, const int* in_sizes, int n_in,
                              void* d_out, int out_size, void* d_ws, size_t ws_size,
                              hipStream_t stream) {
    const float* feats   = (const float*)d_in[0];
    const float* boxes   = (const float*)d_in[1];
    const float* repn_w1 = (const float*)d_in[2];
    const float* repn_b1 = (const float*)d_in[3];
    const float* repn_w2 = (const float*)d_in[4];
    const float* repn_b2 = (const float*)d_in[5];
    const float* gat1_w    = (const float*)d_in[6];
    const float* gat1_asrc = (const float*)d_in[7];
    const float* gat1_adst = (const float*)d_in[8];
    const float* gat1_b    = (const float*)d_in[9];
    const float* gat2_w    = (const float*)d_in[10];
    const float* gat2_asrc = (const float*)d_in[11];
    const float* gat2_adst = (const float*)d_in[12];
    const float* gat2_b    = (const float*)d_in[13];
    const int* kp = (const int*)d_in[14];

    float* out = (float*)d_out;
    float* logits_out = out;
    float* probs_out  = out + 512 * NCLS;
    float* rel_out    = out + 2 * 512 * NCLS;

    // Workspace (floats). Liveness: p [524288,786432) dead after k_rel;
    // h1 [524288,1048576) written at k_aggr1 (after p dead). No other overlap.
    float* wsf  = (float*)d_ws;
    float* hX   = wsf;                 // [0, 524288)
    float* p    = wsf + 524288;        // 512x512
    float* h1   = wsf + 524288;        // alias over dead p
    float* h2   = wsf + 1048576;       // 46592
    float* a_s1 = wsf + 1095680;       // 2048
    float* a_d1 = wsf + 1097728;       // 2048
    float* a_s2 = wsf + 1099776;       // 512
    float* a_d2 = wsf + 1100288;       // 512
    int* ib     = (int*)(wsf + 1100800);
    int* count  = ib;                  // 512 (zeroed)
    int* cursor = ib + 512;            // 512 (zeroed)
    int* nbrs   = ib + 1024;           // 4096
    int* offs   = ib + 5120;           // 520
    int* inlist = ib + 5644;           // 4096

    hipMemsetAsync(count, 0, 1024 * sizeof(int), stream);

    k_p12<<<dim3(8, 32), dim3(256), 0, stream>>>(feats, repn_w1, p);
    k_rel<<<dim3(8, 32), dim3(256), 0, stream>>>(p, repn_w1, repn_b1, repn_w2,
                                                 repn_b2, boxes, rel_out);
    k_topk<<<dim3(512), dim3(64), 0, stream>>>(rel_out, kp, nbrs, count);
    k_scan<<<dim3(1), dim3(512), 0, stream>>>(count, offs);
    k_fill<<<dim3(2), dim3(256), 0, stream>>>(nbrs, kp, offs, cursor, inlist);
    k_gat1<<<dim3(16, 32), dim3(256), 0, stream>>>(feats, boxes, gat1_w, hX);
    k_gred<<<dim3(512), dim3(256), 0, stream>>>(hX, gat1_asrc, gat1_adst, a_s1, a_d1);
    k_aggr1<<<dim3(512), dim3(256), 0, stream>>>(hX, a_s1, a_d1, offs, inlist, gat1_b, h1);
    k_gat2<<<dim3(512), dim3(256), 0, stream>>>(h1, gat2_w, gat2_asrc, gat2_adst,
                                                h2, a_s2, a_d2);
    k_aggr2<<<dim3(512), dim3(128), 0, stream>>>(h2, a_s2, a_d2, offs, inlist, gat2_b,
                                                 logits_out, probs_out);
}

// Round 8
// 308.170 us; speedup vs baseline: 1.1223x; 1.1223x over previous
//
#include <hip/hip_runtime.h>

// Inputs and outputs are float32 (established R1/R3).
#define NCLS 91
#define W1_LD 2052   // repn_w1 row length (2C+4)

// ---------- K0: transpose Wcomb -> WT[k][r] (512 wide) ----------
// Wcomb row r = (r<256 ? repn_w1[r][0:1024] : repn_w1[r-256][1024:2048]).
// Coalesced reads along k; strided writes (fire-and-forget).
__global__ __launch_bounds__(256) void k_wt(const float* __restrict__ w1f,
                                            float* __restrict__ WT) {
    int idx = blockIdx.x * 256 + threadIdx.x;   // 2048 blocks
    int r = idx >> 10, k = idx & 1023;
    float v = w1f[(r < 256 ? r * W1_LD + k : (r - 256) * W1_LD + 1024 + k)];
    WT[k * 512 + r] = v;
}

// ---------- K1: p[i][r] = feats[i] . WT[:,r], streaming (no LDS) ----------
// grid (8 r-slices, 32 i-tiles), 256 thr; thread = 1 row x 4 cols.
__global__ __launch_bounds__(256) void k_p12(const float* __restrict__ feats,
                                             const float* __restrict__ WT,
                                             float* __restrict__ p) {
    int t = threadIdx.x;
    int i = blockIdx.y * 16 + (t >> 4);
    int rc = blockIdx.x * 64 + (t & 15) * 4;
    const float* arow = feats + i * 1024;
    const float* bcol = WT + rc;
    float4 acc = make_float4(0.f, 0.f, 0.f, 0.f);
#pragma unroll 2
    for (int k = 0; k < 1024; k += 4) {
        float4 a4 = *(const float4*)(arow + k);
        float4 b0 = *(const float4*)(bcol + (k + 0) * 512);
        float4 b1 = *(const float4*)(bcol + (k + 1) * 512);
        float4 b2 = *(const float4*)(bcol + (k + 2) * 512);
        float4 b3 = *(const float4*)(bcol + (k + 3) * 512);
        acc.x = fmaf(a4.x, b0.x, acc.x); acc.y = fmaf(a4.x, b0.y, acc.y);
        acc.z = fmaf(a4.x, b0.z, acc.z); acc.w = fmaf(a4.x, b0.w, acc.w);
        acc.x = fmaf(a4.y, b1.x, acc.x); acc.y = fmaf(a4.y, b1.y, acc.y);
        acc.z = fmaf(a4.y, b1.z, acc.z); acc.w = fmaf(a4.y, b1.w, acc.w);
        acc.x = fmaf(a4.z, b2.x, acc.x); acc.y = fmaf(a4.z, b2.y, acc.y);
        acc.z = fmaf(a4.z, b2.z, acc.z); acc.w = fmaf(a4.z, b2.w, acc.w);
        acc.x = fmaf(a4.w, b3.x, acc.x); acc.y = fmaf(a4.w, b3.y, acc.y);
        acc.z = fmaf(a4.w, b3.z, acc.z); acc.w = fmaf(a4.w, b3.w, acc.w);
    }
    *(float4*)(p + i * 512 + rc) = acc;
}

// ---------- K2: rel[i][j] — 16i x 64j tile over 256-dim h ----------
__global__ __launch_bounds__(256) void k_rel(const float* __restrict__ p,
                                             const float* __restrict__ w1f,
                                             const float* __restrict__ b1f,
                                             const float* __restrict__ w2f,
                                             const float* __restrict__ b2f,
                                             const float* __restrict__ boxesf,
                                             float* __restrict__ rel_out) {
    int j0 = blockIdx.x * 64, i0 = blockIdx.y * 16;
    int tid = threadIdx.x, tx = tid & 63, ty = tid >> 6;
    __shared__ float As1[32 * 17];
    __shared__ float Bs[32 * 64];
    __shared__ float Awg[32 * 4];
    __shared__ float Aw2[32];
    float4 bj = *(const float4*)(boxesf + (j0 + tx) * 4);
    float g[4][4];
#pragma unroll
    for (int s = 0; s < 4; ++s) {
        float4 bi = *(const float4*)(boxesf + (i0 + ty * 4 + s) * 4);
        g[s][0] = fabsf(bi.x - bj.x); g[s][1] = fabsf(bi.y - bj.y);
        g[s][2] = fabsf(bi.z - bj.z); g[s][3] = fabsf(bi.w - bj.w);
    }
    float acc[4] = {0.f, 0.f, 0.f, 0.f};
    int ali = tid & 15, alh = (tid >> 4) * 4;
    int blj = tid & 63, blh = (tid >> 6) * 8;
    for (int ch = 0; ch < 8; ++ch) {
        int hb = ch * 32;
        if (tid < 128) {
            float4 v = *(const float4*)(p + (i0 + ali) * 512 + hb + alh);
            float4 b = *(const float4*)(b1f + hb + alh);
            As1[(alh + 0) * 17 + ali] = v.x + b.x;
            As1[(alh + 1) * 17 + ali] = v.y + b.y;
            As1[(alh + 2) * 17 + ali] = v.z + b.z;
            As1[(alh + 3) * 17 + ali] = v.w + b.w;
        }
#pragma unroll
        for (int s = 0; s < 2; ++s) {
            int h = blh + 4 * s;
            float4 u = *(const float4*)(p + (j0 + blj) * 512 + 256 + hb + h);
            Bs[(h + 0) * 64 + blj] = u.x;
            Bs[(h + 1) * 64 + blj] = u.y;
            Bs[(h + 2) * 64 + blj] = u.z;
            Bs[(h + 3) * 64 + blj] = u.w;
        }
        if (tid < 32) {
            int hg = hb + tid;
            *(float4*)(Awg + tid * 4) = *(const float4*)(w1f + hg * W1_LD + 2048);
            Aw2[tid] = w2f[hg];
        }
        __syncthreads();
#pragma unroll
        for (int hh = 0; hh < 32; ++hh) {
            float4 wg = *(const float4*)(Awg + hh * 4);
            float w2v = Aw2[hh];
            float p2v = Bs[hh * 64 + tx];
            float s0 = As1[hh * 17 + ty * 4 + 0];
            float s1 = As1[hh * 17 + ty * 4 + 1];
            float s2 = As1[hh * 17 + ty * 4 + 2];
            float s3 = As1[hh * 17 + ty * 4 + 3];
            float t0 = s0 + p2v;
            t0 = fmaf(g[0][0], wg.x, t0); t0 = fmaf(g[0][1], wg.y, t0);
            t0 = fmaf(g[0][2], wg.z, t0); t0 = fmaf(g[0][3], wg.w, t0);
            acc[0] = fmaf(w2v, fmaxf(t0, 0.f), acc[0]);
            float t1 = s1 + p2v;
            t1 = fmaf(g[1][0], wg.x, t1); t1 = fmaf(g[1][1], wg.y, t1);
            t1 = fmaf(g[1][2], wg.z, t1); t1 = fmaf(g[1][3], wg.w, t1);
            acc[1] = fmaf(w2v, fmaxf(t1, 0.f), acc[1]);
            float t2 = s2 + p2v;
            t2 = fmaf(g[2][0], wg.x, t2); t2 = fmaf(g[2][1], wg.y, t2);
            t2 = fmaf(g[2][2], wg.z, t2); t2 = fmaf(g[2][3], wg.w, t2);
            acc[2] = fmaf(w2v, fmaxf(t2, 0.f), acc[2]);
            float t3 = s3 + p2v;
            t3 = fmaf(g[3][0], wg.x, t3); t3 = fmaf(g[3][1], wg.y, t3);
            t3 = fmaf(g[3][2], wg.z, t3); t3 = fmaf(g[3][3], wg.w, t3);
            acc[3] = fmaf(w2v, fmaxf(t3, 0.f), acc[3]);
        }
        __syncthreads();
    }
    float b2v = b2f[0];
#pragma unroll
    for (int s = 0; s < 4; ++s)
        rel_out[(i0 + ty * 4 + s) * 512 + j0 + tx] = acc[s] + b2v;
}

// ---------- K3: per-row top-(k+1), drop first; count in-degrees ----------
__global__ void k_topk(const float* __restrict__ relf, const int* __restrict__ kp,
                       int* __restrict__ nbrs, int* __restrict__ count) {
    int i = blockIdx.x, lane = threadIdx.x;
    int k = *kp;
    float v[8]; int ids[8];
    for (int q = 0; q < 8; ++q) {
        int j = lane + 64 * q;
        v[q] = relf[i * 512 + j];
        ids[q] = j;
    }
    for (int pick = 0; pick < k + 1; ++pick) {
        float bv = -INFINITY; int bidx = 1 << 30;
        for (int q = 0; q < 8; ++q)
            if (v[q] > bv || (v[q] == bv && ids[q] < bidx)) { bv = v[q]; bidx = ids[q]; }
        for (int off = 32; off > 0; off >>= 1) {
            float ov = __shfl_down(bv, off);
            int oi = __shfl_down(bidx, off);
            if (ov > bv || (ov == bv && oi < bidx)) { bv = ov; bidx = oi; }
        }
        bv = __shfl(bv, 0); bidx = __shfl(bidx, 0);
        if (pick >= 1 && lane == 0) {
            nbrs[i * 8 + (pick - 1)] = bidx;
            atomicAdd(&count[bidx], 1);
        }
        for (int q = 0; q < 8; ++q) if (ids[q] == bidx) v[q] = -INFINITY;
    }
    if (lane == 0) atomicAdd(&count[i], 1);
}

// ---------- K4: exclusive scan ----------
__global__ void k_scan(const int* __restrict__ count, int* __restrict__ offs) {
    __shared__ int s[512];
    int t = threadIdx.x;
    s[t] = count[t];
    __syncthreads();
    for (int off = 1; off < 512; off <<= 1) {
        int v = (t >= off) ? s[t - off] : 0;
        __syncthreads();
        s[t] += v;
        __syncthreads();
    }
    offs[t + 1] = s[t];
    if (t == 0) offs[0] = 0;
}

// ---------- K5: fill in-edge lists ----------
__global__ void k_fill(const int* __restrict__ nbrs, const int* __restrict__ kp,
                       const int* __restrict__ offs, int* __restrict__ cursor,
                       int* __restrict__ inlist) {
    int i = blockIdx.x * blockDim.x + threadIdx.x;
    if (i >= 512) return;
    int k = *kp;
    for (int q = 0; q < k; ++q) {
        int d = nbrs[i * 8 + q] & 511;
        int pos = atomicAdd(&cursor[d], 1);
        inlist[offs[d] + pos] = i;
    }
    int pos = atomicAdd(&cursor[i], 1);
    inlist[offs[i] + pos] = i;
}

// ---------- K6: GAT1 GEMM hX = [feats|geom] @ W, streaming (no LDS) ----------
__global__ __launch_bounds__(256) void k_gat1(const float* __restrict__ feats,
                                              const float* __restrict__ boxesf,
                                              const float* __restrict__ Wg,
                                              float* __restrict__ hX) {
    int t = threadIdx.x;
    int i = blockIdx.y * 16 + (t >> 4);
    int nc = blockIdx.x * 64 + (t & 15) * 4;
    const float* arow = feats + i * 1024;
    const float* bcol = Wg + nc;
    float4 acc = make_float4(0.f, 0.f, 0.f, 0.f);
#pragma unroll 2
    for (int k = 0; k < 1024; k += 4) {
        float4 a4 = *(const float4*)(arow + k);
        float4 b0 = *(const float4*)(bcol + (k + 0) * 1024);
        float4 b1 = *(const float4*)(bcol + (k + 1) * 1024);
        float4 b2 = *(const float4*)(bcol + (k + 2) * 1024);
        float4 b3 = *(const float4*)(bcol + (k + 3) * 1024);
        acc.x = fmaf(a4.x, b0.x, acc.x); acc.y = fmaf(a4.x, b0.y, acc.y);
        acc.z = fmaf(a4.x, b0.z, acc.z); acc.w = fmaf(a4.x, b0.w, acc.w);
        acc.x = fmaf(a4.y, b1.x, acc.x); acc.y = fmaf(a4.y, b1.y, acc.y);
        acc.z = fmaf(a4.y, b1.z, acc.z); acc.w = fmaf(a4.y, b1.w, acc.w);
        acc.x = fmaf(a4.z, b2.x, acc.x); acc.y = fmaf(a4.z, b2.y, acc.y);
        acc.z = fmaf(a4.z, b2.z, acc.z); acc.w = fmaf(a4.z, b2.w, acc.w);
        acc.x = fmaf(a4.w, b3.x, acc.x); acc.y = fmaf(a4.w, b3.y, acc.y);
        acc.z = fmaf(a4.w, b3.z, acc.z); acc.w = fmaf(a4.w, b3.w, acc.w);
    }
    float4 bx = *(const float4*)(boxesf + i * 4);
    float g0 = bx.x / 800.f, g1 = bx.y / 800.f;
    float g2 = bx.z / 800.f - g0, g3 = bx.w / 800.f - g1;
    float4 w0 = *(const float4*)(bcol + 1024 * 1024);
    float4 w1 = *(const float4*)(bcol + 1025 * 1024);
    float4 w2 = *(const float4*)(bcol + 1026 * 1024);
    float4 w3 = *(const float4*)(bcol + 1027 * 1024);
    acc.x += g0 * w0.x + g1 * w1.x + g2 * w2.x + g3 * w3.x;
    acc.y += g0 * w0.y + g1 * w1.y + g2 * w2.y + g3 * w3.y;
    acc.z += g0 * w0.z + g1 * w1.z + g2 * w2.z + g3 * w3.z;
    acc.w += g0 * w0.w + g1 * w1.w + g2 * w2.w + g3 * w3.w;
    *(float4*)(hX + i * 1024 + nc) = acc;
}

// ---------- K6b: a_s1/a_d1 reduction from hX ----------
__global__ __launch_bounds__(256) void k_gred(const float* __restrict__ hX,
                                              const float* __restrict__ asrcf,
                                              const float* __restrict__ adstf,
                                              float* __restrict__ a_s1,
                                              float* __restrict__ a_d1) {
    int i = blockIdx.x, t = threadIdx.x;
    int c = t * 4;
    float4 v = *(const float4*)(hX + i * 1024 + c);
    float4 as4 = *(const float4*)(asrcf + c);
    float4 ad4 = *(const float4*)(adstf + c);
    float ps = v.x * as4.x + v.y * as4.y + v.z * as4.z + v.w * as4.w;
    float pd = v.x * ad4.x + v.y * ad4.y + v.z * ad4.z + v.w * ad4.w;
    int lane = t & 63, q = t >> 6;
    for (int off = 32; off > 0; off >>= 1) {
        ps += __shfl_down(ps, off);
        pd += __shfl_down(pd, off);
    }
    if (lane == 0) {
        a_s1[i * 4 + q] = ps;
        a_d1[i * 4 + q] = pd;
    }
}

// ---------- K8: GAT1 per-dst softmax + aggregate + bias + relu ----------
__global__ void k_aggr1(const float* __restrict__ hX,
                        const float* __restrict__ a_s, const float* __restrict__ a_d,
                        const int* __restrict__ offs, const int* __restrict__ inlist,
                        const float* __restrict__ bias,
                        float* __restrict__ h1) {
    int n = blockIdx.x, t = threadIdx.x;
    int beg = offs[n], deg = offs[n + 1] - beg;
    if (deg > 513) deg = 513;
    __shared__ int srcs[520];
    __shared__ float alpha[520][4];
    __shared__ float sm[4];
    for (int e = t; e < deg; e += 256) srcs[e] = inlist[beg + e] & 511;
    __syncthreads();
    for (int idx = t; idx < deg * 4; idx += 256) {
        int e = idx >> 2, q = idx & 3;
        float sc = a_s[srcs[e] * 4 + q] + a_d[n * 4 + q];
        alpha[e][q] = (sc >= 0.f) ? sc : 0.2f * sc;
    }
    __syncthreads();
    if (t < 4) {
        float m = -INFINITY;
        for (int e = 0; e < deg; ++e) m = fmaxf(m, alpha[e][t]);
        if (!isfinite(m)) m = 0.f;
        float s = 0.f;
        for (int e = 0; e < deg; ++e) { float ex = expf(alpha[e][t] - m); alpha[e][t] = ex; s += ex; }
        sm[t] = s + 1e-16f;
    }
    __syncthreads();
    for (int idx = t; idx < deg * 4; idx += 256) {
        int e = idx >> 2, q = idx & 3;
        alpha[e][q] /= sm[q];
    }
    __syncthreads();
    for (int q = 0; q < 4; ++q) {
        float acc = 0.f;
        for (int e = 0; e < deg; ++e) acc += alpha[e][q] * hX[srcs[e] * 1024 + q * 256 + t];
        h1[n * 1024 + q * 256 + t] = fmaxf(acc + bias[q * 256 + t], 0.f);
    }
}

// ---------- K9: GAT2 GEMM + a_s2/a_d2 ----------
__global__ __launch_bounds__(256) void k_gat2(const float* __restrict__ h1,
                                              const float* __restrict__ Wf,
                                              const float* __restrict__ asrcf,
                                              const float* __restrict__ adstf,
                                              float* __restrict__ h2,
                                              float* __restrict__ a_s2,
                                              float* __restrict__ a_d2) {
    int n = blockIdx.x, t = threadIdx.x;
    __shared__ float xs[1024];
    __shared__ float hbuf[NCLS];
    __shared__ float sred[256], dred[256];
    for (int c = t; c < 1024; c += 256) xs[c] = h1[n * 1024 + c];
    __syncthreads();
    int cls = t & 127, kh = t >> 7;
    float acc = 0.f;
    if (cls < NCLS) {
        const float* wp = Wf + (kh * 512) * NCLS + cls;
        const float* xp = xs + kh * 512;
        float a0 = 0.f, a1 = 0.f, a2 = 0.f, a3 = 0.f;
        for (int c = 0; c < 512; c += 4) {
            a0 = fmaf(xp[c + 0], wp[(c + 0) * NCLS], a0);
            a1 = fmaf(xp[c + 1], wp[(c + 1) * NCLS], a1);
            a2 = fmaf(xp[c + 2], wp[(c + 2) * NCLS], a2);
            a3 = fmaf(xp[c + 3], wp[(c + 3) * NCLS], a3);
        }
        acc = (a0 + a1) + (a2 + a3);
    }
    if (kh == 0 && cls < NCLS) hbuf[cls] = acc;
    __syncthreads();
    float tot = 0.f;
    int act = (kh == 1 && cls < NCLS);
    if (act) { tot = acc + hbuf[cls]; h2[n * NCLS + cls] = tot; }
    sred[t] = act ? tot * asrcf[cls] : 0.f;
    dred[t] = act ? tot * adstf[cls] : 0.f;
    __syncthreads();
    for (int s = 128; s > 0; s >>= 1) {
        if (t < s) { sred[t] += sred[t + s]; dred[t] += dred[t + s]; }
        __syncthreads();
    }
    if (t == 0) { a_s2[n] = sred[0]; a_d2[n] = dred[0]; }
}

// ---------- K10: GAT2 aggregate -> logits + softmax probs ----------
__global__ void k_aggr2(const float* __restrict__ h2,
                        const float* __restrict__ a_s2, const float* __restrict__ a_d2,
                        const int* __restrict__ offs, const int* __restrict__ inlist,
                        const float* __restrict__ bias,
                        float* __restrict__ logits_out,
                        float* __restrict__ probs_out) {
    int n = blockIdx.x, t = threadIdx.x;
    int beg = offs[n], deg = offs[n + 1] - beg;
    if (deg > 513) deg = 513;
    __shared__ int srcs[520];
    __shared__ float alpha[520];
    __shared__ float red[128];
    __shared__ float smden;
    for (int e = t; e < deg; e += 128) {
        int s = inlist[beg + e] & 511;
        srcs[e] = s;
        float sc = a_s2[s] + a_d2[n];
        alpha[e] = (sc >= 0.f) ? sc : 0.2f * sc;
    }
    __syncthreads();
    if (t == 0) {
        float m = -INFINITY;
        for (int e = 0; e < deg; ++e) m = fmaxf(m, alpha[e]);
        if (!isfinite(m)) m = 0.f;
        float s = 0.f;
        for (int e = 0; e < deg; ++e) { float ex = expf(alpha[e] - m); alpha[e] = ex; s += ex; }
        smden = s + 1e-16f;
    }
    __syncthreads();
    float logit = 0.f;
    if (t < NCLS) {
        float acc = 0.f;
        for (int e = 0; e < deg; ++e) acc += alpha[e] * h2[srcs[e] * NCLS + t];
        logit = acc / smden + bias[t];
        logits_out[n * NCLS + t] = logit;
    }
    red[t] = (t < NCLS) ? logit : -INFINITY; __syncthreads();
    for (int s = 64; s > 0; s >>= 1) { if (t < s) red[t] = fmaxf(red[t], red[t + s]); __syncthreads(); }
    float mx = red[0];
    __syncthreads();
    float ex = (t < NCLS) ? expf(logit - mx) : 0.f;
    red[t] = ex; __syncthreads();
    for (int s = 64; s > 0; s >>= 1) { if (t < s) red[t] += red[t + s]; __syncthreads(); }
    float inv = 1.f / red[0];
    if (t < NCLS) probs_out[n * NCLS + t] = ex * inv;
}

// ---------- launch ----------
extern "C" void kernel_launch(void* const* d_in, const int* in_sizes, int n_in,
                              void* d_out, int out_size, void* d_ws, size_t ws_size,
                              hipStream_t stream) {
    const float* feats   = (const float*)d_in[0];
    const float* boxes   = (const float*)d_in[1];
    const float* repn_w1 = (const float*)d_in[2];
    const float* repn_b1 = (const float*)d_in[3];
    const float* repn_w2 = (const float*)d_in[4];
    const float* repn_b2 = (const float*)d_in[5];
    const float* gat1_w    = (const float*)d_in[6];
    const float* gat1_asrc = (const float*)d_in[7];
    const float* gat1_adst = (const float*)d_in[8];
    const float* gat1_b    = (const float*)d_in[9];
    const float* gat2_w    = (const float*)d_in[10];
    const float* gat2_asrc = (const float*)d_in[11];
    const float* gat2_adst = (const float*)d_in[12];
    const float* gat2_b    = (const float*)d_in[13];
    const int* kp = (const int*)d_in[14];

    float* out = (float*)d_out;
    float* logits_out = out;
    float* probs_out  = out + 512 * NCLS;
    float* rel_out    = out + 2 * 512 * NCLS;

    // Workspace (floats). Liveness chain:
    //   p  @ [0,262144)        live k_p12 -> k_rel
    //   WT @ [524288,1048576)  live k_wt  -> k_p12
    //   hX @ [0,524288)        written k_gat1 (p dead)
    //   h1 @ [524288,1048576)  written k_aggr1 (WT dead)
    float* wsf  = (float*)d_ws;
    float* p    = wsf;                 // 512x512
    float* hX   = wsf;                 // 512x1024 (after p dead)
    float* WT   = wsf + 524288;        // 1024x512 transposed Wcomb
    float* h1   = wsf + 524288;        // 512x1024 (after WT dead)
    float* h2   = wsf + 1048576;       // 46592
    float* a_s1 = wsf + 1095680;       // 2048
    float* a_d1 = wsf + 1097728;       // 2048
    float* a_s2 = wsf + 1099776;       // 512
    float* a_d2 = wsf + 1100288;       // 512
    int* ib     = (int*)(wsf + 1100800);
    int* count  = ib;                  // 512 (zeroed)
    int* cursor = ib + 512;            // 512 (zeroed)
    int* nbrs   = ib + 1024;           // 4096
    int* offs   = ib + 5120;           // 520
    int* inlist = ib + 5644;           // 4096

    hipMemsetAsync(count, 0, 1024 * sizeof(int), stream);

    k_wt<<<dim3(2048), dim3(256), 0, stream>>>(repn_w1, WT);
    k_p12<<<dim3(8, 32), dim3(256), 0, stream>>>(feats, WT, p);
    k_rel<<<dim3(8, 32), dim3(256), 0, stream>>>(p, repn_w1, repn_b1, repn_w2,
                                                 repn_b2, boxes, rel_out);
    k_topk<<<dim3(512), dim3(64), 0, stream>>>(rel_out, kp, nbrs, count);
    k_scan<<<dim3(1), dim3(512), 0, stream>>>(count, offs);
    k_fill<<<dim3(2), dim3(256), 0, stream>>>(nbrs, kp, offs, cursor, inlist);
    k_gat1<<<dim3(16, 32), dim3(256), 0, stream>>>(feats, boxes, gat1_w, hX);
    k_gred<<<dim3(512), dim3(256), 0, stream>>>(hX, gat1_asrc, gat1_adst, a_s1, a_d1);
    k_aggr1<<<dim3(512), dim3(256), 0, stream>>>(hX, a_s1, a_d1, offs, inlist, gat1_b, h1);
    k_gat2<<<dim3(512), dim3(256), 0, stream>>>(h1, gat2_w, gat2_asrc, gat2_adst,
                                                h2, a_s2, a_d2);
    k_aggr2<<<dim3(512), dim3(128), 0, stream>>>(h2, a_s2, a_d2, offs, inlist, gat2_b,
                                                 logits_out, probs_out);
}

// Round 9
// 284.879 us; speedup vs baseline: 1.2141x; 1.0818x over previous
//
#include <hip/hip_runtime.h>

// Inputs and outputs are float32 (established R1/R3).
#define NCLS 91
#define W1_LD 2052   // repn_w1 row length (2C+4)

// ---------- K0: transpose Wcomb -> WT[k][r] (512 wide) ----------
__global__ __launch_bounds__(256) void k_wt(const float* __restrict__ w1f,
                                            float* __restrict__ WT) {
    int idx = blockIdx.x * 256 + threadIdx.x;   // 2048 blocks
    int r = idx >> 10, k = idx & 1023;
    float v = w1f[(r < 256 ? r * W1_LD + k : (r - 256) * W1_LD + 1024 + k)];
    WT[k * 512 + r] = v;
}

// ---------- K1: p[i][r] = feats[i] . WT[:,r], streaming ----------
__global__ __launch_bounds__(256) void k_p12(const float* __restrict__ feats,
                                             const float* __restrict__ WT,
                                             float* __restrict__ p) {
    int t = threadIdx.x;
    int i = blockIdx.y * 16 + (t >> 4);
    int rc = blockIdx.x * 64 + (t & 15) * 4;
    const float* arow = feats + i * 1024;
    const float* bcol = WT + rc;
    float4 acc = make_float4(0.f, 0.f, 0.f, 0.f);
#pragma unroll 4
    for (int k = 0; k < 1024; k += 4) {
        float4 a4 = *(const float4*)(arow + k);
        float4 b0 = *(const float4*)(bcol + (k + 0) * 512);
        float4 b1 = *(const float4*)(bcol + (k + 1) * 512);
        float4 b2 = *(const float4*)(bcol + (k + 2) * 512);
        float4 b3 = *(const float4*)(bcol + (k + 3) * 512);
        acc.x = fmaf(a4.x, b0.x, acc.x); acc.y = fmaf(a4.x, b0.y, acc.y);
        acc.z = fmaf(a4.x, b0.z, acc.z); acc.w = fmaf(a4.x, b0.w, acc.w);
        acc.x = fmaf(a4.y, b1.x, acc.x); acc.y = fmaf(a4.y, b1.y, acc.y);
        acc.z = fmaf(a4.y, b1.z, acc.z); acc.w = fmaf(a4.y, b1.w, acc.w);
        acc.x = fmaf(a4.z, b2.x, acc.x); acc.y = fmaf(a4.z, b2.y, acc.y);
        acc.z = fmaf(a4.z, b2.z, acc.z); acc.w = fmaf(a4.z, b2.w, acc.w);
        acc.x = fmaf(a4.w, b3.x, acc.x); acc.y = fmaf(a4.w, b3.y, acc.y);
        acc.z = fmaf(a4.w, b3.z, acc.z); acc.w = fmaf(a4.w, b3.w, acc.w);
    }
    *(float4*)(p + i * 512 + rc) = acc;
}

// ---------- K2: fused rel (blocks 0..511) + gat1 GEMM (blocks 512..1023) ----------
__global__ __launch_bounds__(256) void k_mix(const float* __restrict__ p,
                                             const float* __restrict__ w1f,
                                             const float* __restrict__ b1f,
                                             const float* __restrict__ w2f,
                                             const float* __restrict__ b2f,
                                             const float* __restrict__ boxesf,
                                             const float* __restrict__ feats,
                                             const float* __restrict__ Wg,
                                             float* __restrict__ rel_out,
                                             float* __restrict__ hX) {
    int b = blockIdx.x, t = threadIdx.x;
    if (b < 512) {
        // ----- rel: 8 i x 64 j tile -----
        int j0 = (b & 7) * 64, i0 = (b >> 3) * 8;
        int tx = t & 63, ty = t >> 6;   // ty: 2 rows each
        __shared__ float As1[32 * 9];
        __shared__ float Bs[32 * 64];
        __shared__ float Awg[32 * 4];
        __shared__ float Aw2[32];
        float4 bj = *(const float4*)(boxesf + (j0 + tx) * 4);
        float g[2][4];
#pragma unroll
        for (int s = 0; s < 2; ++s) {
            float4 bi = *(const float4*)(boxesf + (i0 + ty * 2 + s) * 4);
            g[s][0] = fabsf(bi.x - bj.x); g[s][1] = fabsf(bi.y - bj.y);
            g[s][2] = fabsf(bi.z - bj.z); g[s][3] = fabsf(bi.w - bj.w);
        }
        float acc0 = 0.f, acc1 = 0.f;
        int ali = t & 7, alh = (t >> 3) * 4;      // t<64: 8 i x 8 h-groups
        int blj = t & 63, blh = (t >> 6) * 8;
        for (int ch = 0; ch < 8; ++ch) {
            int hb = ch * 32;
            if (t < 64) {
                float4 v = *(const float4*)(p + (i0 + ali) * 512 + hb + alh);
                float4 bb = *(const float4*)(b1f + hb + alh);
                As1[(alh + 0) * 9 + ali] = v.x + bb.x;
                As1[(alh + 1) * 9 + ali] = v.y + bb.y;
                As1[(alh + 2) * 9 + ali] = v.z + bb.z;
                As1[(alh + 3) * 9 + ali] = v.w + bb.w;
            }
#pragma unroll
            for (int s = 0; s < 2; ++s) {
                int h = blh + 4 * s;
                float4 u = *(const float4*)(p + (j0 + blj) * 512 + 256 + hb + h);
                Bs[(h + 0) * 64 + blj] = u.x;
                Bs[(h + 1) * 64 + blj] = u.y;
                Bs[(h + 2) * 64 + blj] = u.z;
                Bs[(h + 3) * 64 + blj] = u.w;
            }
            if (t < 32) {
                int hg = hb + t;
                *(float4*)(Awg + t * 4) = *(const float4*)(w1f + hg * W1_LD + 2048);
                Aw2[t] = w2f[hg];
            }
            __syncthreads();
#pragma unroll
            for (int hh = 0; hh < 32; ++hh) {
                float4 wg = *(const float4*)(Awg + hh * 4);
                float w2v = Aw2[hh];
                float p2v = Bs[hh * 64 + tx];
                float s0 = As1[hh * 9 + ty * 2 + 0];
                float s1 = As1[hh * 9 + ty * 2 + 1];
                float t0 = s0 + p2v;
                t0 = fmaf(g[0][0], wg.x, t0); t0 = fmaf(g[0][1], wg.y, t0);
                t0 = fmaf(g[0][2], wg.z, t0); t0 = fmaf(g[0][3], wg.w, t0);
                acc0 = fmaf(w2v, fmaxf(t0, 0.f), acc0);
                float t1 = s1 + p2v;
                t1 = fmaf(g[1][0], wg.x, t1); t1 = fmaf(g[1][1], wg.y, t1);
                t1 = fmaf(g[1][2], wg.z, t1); t1 = fmaf(g[1][3], wg.w, t1);
                acc1 = fmaf(w2v, fmaxf(t1, 0.f), acc1);
            }
            __syncthreads();
        }
        float b2v = b2f[0];
        rel_out[(i0 + ty * 2 + 0) * 512 + j0 + tx] = acc0 + b2v;
        rel_out[(i0 + ty * 2 + 1) * 512 + j0 + tx] = acc1 + b2v;
    } else {
        // ----- gat1: streaming GEMM + geom epilogue -----
        int bb = b - 512;
        int i = (bb >> 4) * 16 + (t >> 4);
        int nc = (bb & 15) * 64 + (t & 15) * 4;
        const float* arow = feats + i * 1024;
        const float* bcol = Wg + nc;
        float4 acc = make_float4(0.f, 0.f, 0.f, 0.f);
#pragma unroll 2
        for (int k = 0; k < 1024; k += 4) {
            float4 a4 = *(const float4*)(arow + k);
            float4 b0 = *(const float4*)(bcol + (k + 0) * 1024);
            float4 b1 = *(const float4*)(bcol + (k + 1) * 1024);
            float4 b2 = *(const float4*)(bcol + (k + 2) * 1024);
            float4 b3 = *(const float4*)(bcol + (k + 3) * 1024);
            acc.x = fmaf(a4.x, b0.x, acc.x); acc.y = fmaf(a4.x, b0.y, acc.y);
            acc.z = fmaf(a4.x, b0.z, acc.z); acc.w = fmaf(a4.x, b0.w, acc.w);
            acc.x = fmaf(a4.y, b1.x, acc.x); acc.y = fmaf(a4.y, b1.y, acc.y);
            acc.z = fmaf(a4.y, b1.z, acc.z); acc.w = fmaf(a4.y, b1.w, acc.w);
            acc.x = fmaf(a4.z, b2.x, acc.x); acc.y = fmaf(a4.z, b2.y, acc.y);
            acc.z = fmaf(a4.z, b2.z, acc.z); acc.w = fmaf(a4.z, b2.w, acc.w);
            acc.x = fmaf(a4.w, b3.x, acc.x); acc.y = fmaf(a4.w, b3.y, acc.y);
            acc.z = fmaf(a4.w, b3.z, acc.z); acc.w = fmaf(a4.w, b3.w, acc.w);
        }
        float4 bx = *(const float4*)(boxesf + i * 4);
        float g0 = bx.x / 800.f, g1 = bx.y / 800.f;
        float g2 = bx.z / 800.f - g0, g3 = bx.w / 800.f - g1;
        float4 w0 = *(const float4*)(bcol + 1024 * 1024);
        float4 w1 = *(const float4*)(bcol + 1025 * 1024);
        float4 w2 = *(const float4*)(bcol + 1026 * 1024);
        float4 w3 = *(const float4*)(bcol + 1027 * 1024);
        acc.x += g0 * w0.x + g1 * w1.x + g2 * w2.x + g3 * w3.x;
        acc.y += g0 * w0.y + g1 * w1.y + g2 * w2.y + g3 * w3.y;
        acc.z += g0 * w0.z + g1 * w1.z + g2 * w2.z + g3 * w3.z;
        acc.w += g0 * w0.w + g1 * w1.w + g2 * w2.w + g3 * w3.w;
        *(float4*)(hX + i * 1024 + nc) = acc;
    }
}

// ---------- K3: fused topk (blocks 0..511) + a_s1/a_d1 reduce (512..1023) ----------
__global__ __launch_bounds__(256) void k_tg(const float* __restrict__ relf,
                                            const int* __restrict__ kp,
                                            const float* __restrict__ hX,
                                            const float* __restrict__ asrcf,
                                            const float* __restrict__ adstf,
                                            int* __restrict__ nbrs, int* __restrict__ count,
                                            float* __restrict__ a_s1, float* __restrict__ a_d1) {
    int b = blockIdx.x, t = threadIdx.x;
    if (b < 512) {
        if (t >= 64) return;
        int i = b, lane = t;
        int k = *kp;
        float v[8]; int ids[8];
        for (int q = 0; q < 8; ++q) {
            int j = lane + 64 * q;
            v[q] = relf[i * 512 + j];
            ids[q] = j;
        }
        for (int pick = 0; pick < k + 1; ++pick) {
            float bv = -INFINITY; int bidx = 1 << 30;
            for (int q = 0; q < 8; ++q)
                if (v[q] > bv || (v[q] == bv && ids[q] < bidx)) { bv = v[q]; bidx = ids[q]; }
            for (int off = 32; off > 0; off >>= 1) {
                float ov = __shfl_down(bv, off);
                int oi = __shfl_down(bidx, off);
                if (ov > bv || (ov == bv && oi < bidx)) { bv = ov; bidx = oi; }
            }
            bv = __shfl(bv, 0); bidx = __shfl(bidx, 0);
            if (pick >= 1 && lane == 0) {
                nbrs[i * 8 + (pick - 1)] = bidx;
                atomicAdd(&count[bidx], 1);
            }
            for (int q = 0; q < 8; ++q) if (ids[q] == bidx) v[q] = -INFINITY;
        }
        if (lane == 0) atomicAdd(&count[i], 1);
    } else {
        int i = b - 512;
        int c = t * 4;
        float4 v = *(const float4*)(hX + i * 1024 + c);
        float4 as4 = *(const float4*)(asrcf + c);
        float4 ad4 = *(const float4*)(adstf + c);
        float ps = v.x * as4.x + v.y * as4.y + v.z * as4.z + v.w * as4.w;
        float pd = v.x * ad4.x + v.y * ad4.y + v.z * ad4.z + v.w * ad4.w;
        int lane = t & 63, q = t >> 6;
        for (int off = 32; off > 0; off >>= 1) {
            ps += __shfl_down(ps, off);
            pd += __shfl_down(pd, off);
        }
        if (lane == 0) {
            a_s1[i * 4 + q] = ps;
            a_d1[i * 4 + q] = pd;
        }
    }
}

// ---------- K4: scan + fill in one block (LDS cursors) ----------
__global__ __launch_bounds__(512) void k_graph(const int* __restrict__ count,
                                               const int* __restrict__ nbrs,
                                               const int* __restrict__ kp,
                                               int* __restrict__ offs,
                                               int* __restrict__ inlist) {
    __shared__ int s[512];
    __shared__ int cur[512];
    int t = threadIdx.x;
    s[t] = count[t];
    __syncthreads();
    for (int off = 1; off < 512; off <<= 1) {
        int v = (t >= off) ? s[t - off] : 0;
        __syncthreads();
        s[t] += v;
        __syncthreads();
    }
    offs[t + 1] = s[t];
    if (t == 0) offs[0] = 0;
    cur[t] = (t == 0) ? 0 : s[t - 1];
    __syncthreads();
    int k = *kp;
    for (int q = 0; q < k; ++q) {
        int d = nbrs[t * 8 + q] & 511;
        int pos = atomicAdd(&cur[d], 1);
        inlist[pos] = t;
    }
    int pos = atomicAdd(&cur[t], 1);
    inlist[pos] = t;
}

// ---------- K5: GAT1 softmax+aggregate, one (node, head) per 64-thr block ----------
__global__ __launch_bounds__(64) void k_aggr1(const float* __restrict__ hX,
                                              const float* __restrict__ a_s,
                                              const float* __restrict__ a_d,
                                              const int* __restrict__ offs,
                                              const int* __restrict__ inlist,
                                              const float* __restrict__ bias,
                                              float* __restrict__ h1) {
    int n = blockIdx.x, q = blockIdx.y, lane = threadIdx.x;
    int beg = offs[n], deg = offs[n + 1] - beg;
    if (deg > 513) deg = 513;
    __shared__ int srcs[520];
    __shared__ float alpha[520];
    float adn = a_d[n * 4 + q];
    float lm = -INFINITY;
    for (int e = lane; e < deg; e += 64) {
        int s = inlist[beg + e] & 511;
        srcs[e] = s;
        float sc = a_s[s * 4 + q] + adn;
        sc = (sc >= 0.f) ? sc : 0.2f * sc;
        alpha[e] = sc;
        lm = fmaxf(lm, sc);
    }
    for (int off = 32; off > 0; off >>= 1) lm = fmaxf(lm, __shfl_down(lm, off));
    lm = __shfl(lm, 0);
    if (!isfinite(lm)) lm = 0.f;
    __syncthreads();
    float ls = 0.f;
    for (int e = lane; e < deg; e += 64) {
        float ex = expf(alpha[e] - lm);
        alpha[e] = ex;
        ls += ex;
    }
    for (int off = 32; off > 0; off >>= 1) ls += __shfl_down(ls, off);
    ls = __shfl(ls, 0);
    float inv = 1.f / (ls + 1e-16f);
    __syncthreads();
    int c = q * 256 + lane * 4;
    float ax = 0.f, ay = 0.f, az = 0.f, aw = 0.f;
    for (int e = 0; e < deg; ++e) {
        float a = alpha[e] * inv;
        float4 v = *(const float4*)(hX + srcs[e] * 1024 + c);
        ax = fmaf(a, v.x, ax); ay = fmaf(a, v.y, ay);
        az = fmaf(a, v.z, az); aw = fmaf(a, v.w, aw);
    }
    float4 bb = *(const float4*)(bias + c);
    float4 o;
    o.x = fmaxf(ax + bb.x, 0.f); o.y = fmaxf(ay + bb.y, 0.f);
    o.z = fmaxf(az + bb.z, 0.f); o.w = fmaxf(aw + bb.w, 0.f);
    *(float4*)(h1 + n * 1024 + c) = o;
}

// ---------- K6: GAT2 GEMM + a_s2/a_d2 ----------
__global__ __launch_bounds__(256) void k_gat2(const float* __restrict__ h1,
                                              const float* __restrict__ Wf,
                                              const float* __restrict__ asrcf,
                                              const float* __restrict__ adstf,
                                              float* __restrict__ h2,
                                              float* __restrict__ a_s2,
                                              float* __restrict__ a_d2) {
    int n = blockIdx.x, t = threadIdx.x;
    __shared__ float xs[1024];
    __shared__ float hbuf[NCLS];
    __shared__ float sred[256], dred[256];
    for (int c = t; c < 1024; c += 256) xs[c] = h1[n * 1024 + c];
    __syncthreads();
    int cls = t & 127, kh = t >> 7;
    float acc = 0.f;
    if (cls < NCLS) {
        const float* wp = Wf + (kh * 512) * NCLS + cls;
        const float* xp = xs + kh * 512;
        float a0 = 0.f, a1 = 0.f, a2 = 0.f, a3 = 0.f;
        for (int c = 0; c < 512; c += 4) {
            a0 = fmaf(xp[c + 0], wp[(c + 0) * NCLS], a0);
            a1 = fmaf(xp[c + 1], wp[(c + 1) * NCLS], a1);
            a2 = fmaf(xp[c + 2], wp[(c + 2) * NCLS], a2);
            a3 = fmaf(xp[c + 3], wp[(c + 3) * NCLS], a3);
        }
        acc = (a0 + a1) + (a2 + a3);
    }
    if (kh == 0 && cls < NCLS) hbuf[cls] = acc;
    __syncthreads();
    float tot = 0.f;
    int act = (kh == 1 && cls < NCLS);
    if (act) { tot = acc + hbuf[cls]; h2[n * NCLS + cls] = tot; }
    sred[t] = act ? tot * asrcf[cls] : 0.f;
    dred[t] = act ? tot * adstf[cls] : 0.f;
    __syncthreads();
    for (int s = 128; s > 0; s >>= 1) {
        if (t < s) { sred[t] += sred[t + s]; dred[t] += dred[t + s]; }
        __syncthreads();
    }
    if (t == 0) { a_s2[n] = sred[0]; a_d2[n] = dred[0]; }
}

// ---------- K7: GAT2 aggregate -> logits + softmax probs ----------
__global__ void k_aggr2(const float* __restrict__ h2,
                        const float* __restrict__ a_s2, const float* __restrict__ a_d2,
                        const int* __restrict__ offs, const int* __restrict__ inlist,
                        const float* __restrict__ bias,
                        float* __restrict__ logits_out,
                        float* __restrict__ probs_out) {
    int n = blockIdx.x, t = threadIdx.x;
    int beg = offs[n], deg = offs[n + 1] - beg;
    if (deg > 513) deg = 513;
    __shared__ int srcs[520];
    __shared__ float alpha[520];
    __shared__ float red[128];
    __shared__ float smden;
    for (int e = t; e < deg; e += 128) {
        int s = inlist[beg + e] & 511;
        srcs[e] = s;
        float sc = a_s2[s] + a_d2[n];
        alpha[e] = (sc >= 0.f) ? sc : 0.2f * sc;
    }
    __syncthreads();
    if (t == 0) {
        float m = -INFINITY;
        for (int e = 0; e < deg; ++e) m = fmaxf(m, alpha[e]);
        if (!isfinite(m)) m = 0.f;
        float s = 0.f;
        for (int e = 0; e < deg; ++e) { float ex = expf(alpha[e] - m); alpha[e] = ex; s += ex; }
        smden = s + 1e-16f;
    }
    __syncthreads();
    float logit = 0.f;
    if (t < NCLS) {
        float acc = 0.f;
        for (int e = 0; e < deg; ++e) acc += alpha[e] * h2[srcs[e] * NCLS + t];
        logit = acc / smden + bias[t];
        logits_out[n * NCLS + t] = logit;
    }
    red[t] = (t < NCLS) ? logit : -INFINITY; __syncthreads();
    for (int s = 64; s > 0; s >>= 1) { if (t < s) red[t] = fmaxf(red[t], red[t + s]); __syncthreads(); }
    float mx = red[0];
    __syncthreads();
    float ex = (t < NCLS) ? expf(logit - mx) : 0.f;
    red[t] = ex; __syncthreads();
    for (int s = 64; s > 0; s >>= 1) { if (t < s) red[t] += red[t + s]; __syncthreads(); }
    float inv = 1.f / red[0];
    if (t < NCLS) probs_out[n * NCLS + t] = ex * inv;
}

// ---------- launch ----------
extern "C" void kernel_launch(void* const* d_in, const int* in_sizes, int n_in,
                              void* d_out, int out_size, void* d_ws, size_t ws_size,
                              hipStream_t stream) {
    const float* feats   = (const float*)d_in[0];
    const float* boxes   = (const float*)d_in[1];
    const float* repn_w1 = (const float*)d_in[2];
    const float* repn_b1 = (const float*)d_in[3];
    const float* repn_w2 = (const float*)d_in[4];
    const float* repn_b2 = (const float*)d_in[5];
    const float* gat1_w    = (const float*)d_in[6];
    const float* gat1_asrc = (const float*)d_in[7];
    const float* gat1_adst = (const float*)d_in[8];
    const float* gat1_b    = (const float*)d_in[9];
    const float* gat2_w    = (const float*)d_in[10];
    const float* gat2_asrc = (const float*)d_in[11];
    const float* gat2_adst = (const float*)d_in[12];
    const float* gat2_b    = (const float*)d_in[13];
    const int* kp = (const int*)d_in[14];

    float* out = (float*)d_out;
    float* logits_out = out;
    float* probs_out  = out + 512 * NCLS;
    float* rel_out    = out + 2 * 512 * NCLS;

    // Workspace (floats). Liveness:
    //   p  @ [0,262144)        k_p12 -> k_mix(rel part)
    //   WT @ [524288,1048576)  k_wt -> k_p12
    //   hX @ [524288,1048576)  written k_mix(gat1 part; WT dead), read k_tg/k_aggr1
    //   h1 @ [0,524288)        written k_aggr1 (p dead)
    float* wsf  = (float*)d_ws;
    float* p    = wsf;                 // 512x512
    float* h1   = wsf;                 // 512x1024 (after p dead)
    float* WT   = wsf + 524288;        // 1024x512
    float* hX   = wsf + 524288;        // 512x1024 (after WT dead)
    float* h2   = wsf + 1048576;       // 46592
    float* a_s1 = wsf + 1095680;       // 2048
    float* a_d1 = wsf + 1097728;       // 2048
    float* a_s2 = wsf + 1099776;       // 512
    float* a_d2 = wsf + 1100288;       // 512
    int* ib     = (int*)(wsf + 1100800);
    int* count  = ib;                  // 512 (zeroed)
    int* nbrs   = ib + 512;            // 4096
    int* offs   = ib + 4608;           // 520
    int* inlist = ib + 5128;           // 4096

    hipMemsetAsync(count, 0, 512 * sizeof(int), stream);

    k_wt<<<dim3(2048), dim3(256), 0, stream>>>(repn_w1, WT);
    k_p12<<<dim3(8, 32), dim3(256), 0, stream>>>(feats, WT, p);
    k_mix<<<dim3(1024), dim3(256), 0, stream>>>(p, repn_w1, repn_b1, repn_w2, repn_b2,
                                                boxes, feats, gat1_w, rel_out, hX);
    k_tg<<<dim3(1024), dim3(256), 0, stream>>>(rel_out, kp, hX, gat1_asrc, gat1_adst,
                                               nbrs, count, a_s1, a_d1);
    k_graph<<<dim3(1), dim3(512), 0, stream>>>(count, nbrs, kp, offs, inlist);
    k_aggr1<<<dim3(512, 4), dim3(64), 0, stream>>>(hX, a_s1, a_d1, offs, inlist,
                                                   gat1_b, h1);
    k_gat2<<<dim3(512), dim3(256), 0, stream>>>(h1, gat2_w, gat2_asrc, gat2_adst,
                                                h2, a_s2, a_d2);
    k_aggr2<<<dim3(512), dim3(128), 0, stream>>>(h2, a_s2, a_d2, offs, inlist, gat2_b,
                                                 logits_out, probs_out);
}